// Round 2
// baseline (221.250 us; speedup 1.0000x reference)
//
#include <hip/hip_runtime.h>
#include <hip/hip_bf16.h>

typedef __bf16 bf16x8 __attribute__((ext_vector_type(8)));
typedef float  f32x4  __attribute__((ext_vector_type(4)));

#define BS 64       // rotation block size
#define RB 64       // number of rotation blocks
#define NELEM 2016  // strict upper-triangle element count
#define DD 4096     // feature dim
#define MROWS 16384 // 4 * 4096 rows
#define TILES 8     // 16-row tiles per wave

// ---------------------------------------------------------------------------
// Kernel A: build R[r] = I + 2Q + 2Q^2 + 2Q^3 + 2Q^4 (fp32), then emit R in
// bf16 pre-packed MFMA B-fragment order:
//   Rpk[((rblk*8 + kf*4 + n)*64 + lane)*8 + j] = bf16( R[32*kf + 8*(lane>>4) + j][16*n + (lane&15)] )
// so apply waves load their 8 B-frags as 8 coalesced 16B reads.
// One block per rblk, 512 threads: thread = (col j = t&63, 8 rows).
// ---------------------------------------------------------------------------
__global__ __launch_bounds__(512) void rot_kernel(const float* __restrict__ w,
                                                  __bf16* __restrict__ Rpk) {
    const int blk = blockIdx.x;
    const int t   = threadIdx.x;
    __shared__ float Q[BS * BS];
    __shared__ float B0[BS * BS];
    __shared__ float B1[BS * BS];
    const float* wb = w + blk * NELEM;

    // Build skew-symmetric Q from strict upper triangle.
    for (int e = t; e < BS * BS; e += 512) {
        const int i = e >> 6, j = e & 63;
        float v = 0.f;
        if (i < j)      v =  wb[63 * i - (i * (i - 1)) / 2 + (j - i - 1)];
        else if (i > j) v = -wb[63 * j - (j * (j - 1)) / 2 + (i - j - 1)];
        Q[e] = v;
    }
    __syncthreads();

    const int j     = t & 63;        // column (lane index within wave)
    const int ibase = (t >> 6) * 8;  // 8 rows per thread

    float qcol[BS];
#pragma unroll
    for (int k = 0; k < BS; ++k) qcol[k] = Q[k * BS + j];

    float racc[8];
#pragma unroll
    for (int s = 0; s < 8; ++s) {
        const int i = ibase + s;
        racc[s] = (i == j ? 1.f : 0.f) + 2.f * Q[i * BS + j];
    }

    // Q^2, Q^3, Q^4 accumulated with weight 2. Reads of P are wave-uniform
    // broadcasts; writes stride-1 (2-way bank alias = free).
    const float* P = Q;
    float*       T = B0;
    for (int pass = 0; pass < 3; ++pass) {
#pragma unroll
        for (int s = 0; s < 8; ++s) {
            const int i = ibase + s;
            float sum = 0.f;
#pragma unroll 8
            for (int k = 0; k < BS; ++k) sum += P[i * BS + k] * qcol[k];
            T[i * BS + j] = sum;
            racc[s] += 2.f * sum;
        }
        __syncthreads();
        P = T;
        T = (pass == 0) ? B1 : B0;
    }

    // Scatter-store into packed bf16 B-fragment layout.
#pragma unroll
    for (int s = 0; s < 8; ++s) {
        const int i  = ibase + s;         // k index
        const int kf = i >> 5;            // K=32 fragment half
        const int g  = (i >> 3) & 3;      // lane group
        const int jj = i & 7;             // element within lane
        const int lane = 16 * g + (j & 15);
        const int n    = j >> 4;          // 16-col fragment
        Rpk[(size_t)((blk * 8 + kf * 4 + n) * 64 + lane) * 8 + jj] = (__bf16)racc[s];
    }
}

// ---------------------------------------------------------------------------
// Kernel B: y[row, rblk*64+c] = sum_k x[row, rblk*64+k] * R[rblk][k][c]
// via mfma_f32_16x16x32_bf16. One wave owns (rblk, 8 tiles of 16 rows,
// all 64 cols). R held entirely in registers (8 B-frags). X loaded straight
// from global to registers in A-frag order (each byte read exactly once).
// No LDS, no barriers. Prefetch next tile's loads before computing current.
// ---------------------------------------------------------------------------
__global__ __launch_bounds__(256) void apply_kernel(const float* __restrict__ x,
                                                    const __bf16* __restrict__ Rpk,
                                                    float* __restrict__ y) {
    const int tid  = threadIdx.x;
    const int l    = tid & 63;
    const int W    = blockIdx.x * 4 + (tid >> 6);
    const int rblk = W & 63;
    const int rg   = W >> 6;          // 0..127 row-groups of 128 rows
    const int g    = l >> 4;
    const int c    = l & 15;

    // Load the 8 B-fragments of R[rblk] (coalesced 16B per lane).
    bf16x8 bfrag[2][4];
    const bf16x8* rp = reinterpret_cast<const bf16x8*>(Rpk) + (size_t)rblk * 8 * 64 + l;
#pragma unroll
    for (int kf = 0; kf < 2; ++kf)
#pragma unroll
        for (int n = 0; n < 4; ++n)
            bfrag[kf][n] = rp[(kf * 4 + n) * 64];

    const long rowbase = (long)rg * (TILES * 16);
    // Lane's A-frag source: row = l&15 within tile, k-bytes at g*8 (+kf*32).
    const float* xlane = x + (rowbase + (l & 15)) * (long)DD + rblk * 64 + g * 8;

    const f32x4 zero = {0.f, 0.f, 0.f, 0.f};

    f32x4 v[4], vn[4];
#pragma unroll
    for (int q = 0; q < 4; ++q)
        v[q] = *reinterpret_cast<const f32x4*>(xlane + (q >> 1) * 32 + (q & 1) * 4);

#pragma unroll
    for (int t = 0; t < TILES; ++t) {
        // Prefetch next tile's X (independent of compute below).
        if (t + 1 < TILES) {
            const float* xp = xlane + (long)(t + 1) * 16 * DD;
#pragma unroll
            for (int q = 0; q < 4; ++q)
                vn[q] = *reinterpret_cast<const f32x4*>(xp + (q >> 1) * 32 + (q & 1) * 4);
        }

        // Convert to bf16 A-fragments (elements j=0..7 <-> k = 32kf+8g+j).
        bf16x8 a0, a1;
#pragma unroll
        for (int e = 0; e < 4; ++e) {
            a0[e]     = (__bf16)v[0][e];
            a0[e + 4] = (__bf16)v[1][e];
            a1[e]     = (__bf16)v[2][e];
            a1[e + 4] = (__bf16)v[3][e];
        }

        f32x4 acc[4];
#pragma unroll
        for (int n = 0; n < 4; ++n)
            acc[n] = __builtin_amdgcn_mfma_f32_16x16x32_bf16(a0, bfrag[0][n], zero, 0, 0, 0);
#pragma unroll
        for (int n = 0; n < 4; ++n)
            acc[n] = __builtin_amdgcn_mfma_f32_16x16x32_bf16(a1, bfrag[1][n], acc[n], 0, 0, 0);

        // Store: lane holds rows 4g+i, col c+16n of this 16x64 tile.
        float* yl = y + (rowbase + t * 16 + 4 * g) * (long)DD + rblk * 64 + c;
#pragma unroll
        for (int n = 0; n < 4; ++n)
#pragma unroll
            for (int i = 0; i < 4; ++i)
                yl[(long)i * DD + n * 16] = acc[n][i];

#pragma unroll
        for (int q = 0; q < 4; ++q) v[q] = vn[q];
    }
}

extern "C" void kernel_launch(void* const* d_in, const int* in_sizes, int n_in,
                              void* d_out, int out_size, void* d_ws, size_t ws_size,
                              hipStream_t stream) {
    (void)in_sizes; (void)n_in; (void)out_size; (void)ws_size;
    const float* x = (const float*)d_in[0];
    const float* w = (const float*)d_in[1];
    float* y = (float*)d_out;
    __bf16* Rpk = (__bf16*)d_ws;   // 64 rblk * 8 frags * 64 lanes * 8 bf16 = 512 KB

    rot_kernel<<<RB, 512, 0, stream>>>(w, Rpk);

    const int waves  = RB * (MROWS / (TILES * 16));  // 64 * 128 = 8192
    const int blocks = waves / 4;                    // 2048 blocks of 256 thr
    apply_kernel<<<blocks, 256, 0, stream>>>(x, Rpk, y);
}

// Round 3
// 124.356 us; speedup vs baseline: 1.7792x; 1.7792x over previous
//
#include <hip/hip_runtime.h>
#include <hip/hip_bf16.h>

typedef __bf16 bf16x8 __attribute__((ext_vector_type(8)));
typedef float  f32x4  __attribute__((ext_vector_type(4)));

#define BS 64       // rotation block size
#define RB 64       // number of rotation blocks
#define NELEM 2016  // strict upper-triangle element count
#define DD 4096     // feature dim
#define MROWS 16384 // 4 * 4096 rows
#define TILES 8     // 16-row tiles per wave

// ---------------------------------------------------------------------------
// Kernel A: build R[r] = I + 2Q + 2Q^2 + 2Q^3 + 2Q^4 (fp32), emit bf16 R in
// pre-packed MFMA B-fragment order:
//   Rpk[((rblk*8 + kf*4 + n)*64 + lane)*8 + jj] =
//       bf16( R[32*kf + 8*(lane>>4) + jj][16*n + (lane&15)] )
// One block per rblk, 256 threads: thread = (col j = t&63, 16 rows).
// NOTE: every array index below is compile-time (FULL unrolls) -> registers.
// Partial unroll demotes qcol[] to scratch (rule #20) and cost ~100us in r2.
// ---------------------------------------------------------------------------
__global__ __launch_bounds__(256) void rot_kernel(const float* __restrict__ w,
                                                  __bf16* __restrict__ Rpk) {
    const int blk = blockIdx.x;
    const int t   = threadIdx.x;
    __shared__ float Q [BS * BS];
    __shared__ float B0[BS * BS];
    __shared__ float B1[BS * BS];
    const float* wb = w + blk * NELEM;

    // Build skew-symmetric Q from strict upper triangle.
    for (int e = t; e < BS * BS; e += 256) {
        const int i = e >> 6, j = e & 63;
        float v = 0.f;
        if (i < j)      v =  wb[63 * i - (i * (i - 1)) / 2 + (j - i - 1)];
        else if (i > j) v = -wb[63 * j - (j * (j - 1)) / 2 + (i - j - 1)];
        Q[e] = v;
    }
    __syncthreads();

    const int j     = t & 63;        // column
    const int ibase = (t >> 6) << 4; // 16 rows per thread

    // Q's column j cached in registers (reused by all 3 matmuls).
    float qcol[BS];
#pragma unroll
    for (int k = 0; k < BS; ++k) qcol[k] = Q[k * BS + j];

    float racc[16];
#pragma unroll
    for (int s = 0; s < 16; ++s) {
        const int i = ibase + s;
        racc[s] = (i == j ? 1.f : 0.f) + 2.f * Q[i * BS + j];
    }

    // Q^2, Q^3, Q^4 accumulated with weight 2. P reads are wave-uniform
    // broadcasts; qcol in registers.
    const float* P = Q;
    float*       T = B0;
    for (int pass = 0; pass < 3; ++pass) {
#pragma unroll
        for (int s = 0; s < 16; ++s) {
            const int i = ibase + s;
            float sum = 0.f;
#pragma unroll
            for (int k = 0; k < BS; ++k) sum += P[i * BS + k] * qcol[k];
            T[i * BS + j] = sum;
            racc[s] += 2.f * sum;
        }
        __syncthreads();
        P = T;
        T = (pass == 0) ? B1 : B0;
    }

    // Scatter-store into packed bf16 B-fragment layout.
#pragma unroll
    for (int s = 0; s < 16; ++s) {
        const int i  = ibase + s;        // k index of R[k][c]
        const int kf = i >> 5;           // K=32 fragment half
        const int g  = (i >> 3) & 3;     // lane group
        const int jj = i & 7;            // element within lane
        const int lane = 16 * g + (j & 15);
        const int n    = j >> 4;         // 16-col fragment
        Rpk[(size_t)((blk * 8 + kf * 4 + n) * 64 + lane) * 8 + jj] = (__bf16)racc[s];
    }
}

// ---------------------------------------------------------------------------
// Kernel B: y[row, rblk*64+c] = sum_k x[row, rblk*64+k] * R[rblk][k][c]
// via mfma_f32_16x16x32_bf16. One wave owns (rblk, 8 tiles of 16 rows,
// all 64 cols). R held entirely in registers (8 B-frags). X loaded straight
// from global to registers in A-frag order (each byte read exactly once).
// No LDS, no barriers. y stores are nontemporal (write-once stream) to keep
// L2/L3 capacity for x.
// ---------------------------------------------------------------------------
__global__ __launch_bounds__(256) void apply_kernel(const float* __restrict__ x,
                                                    const __bf16* __restrict__ Rpk,
                                                    float* __restrict__ y) {
    const int tid  = threadIdx.x;
    const int l    = tid & 63;
    const int W    = blockIdx.x * 4 + (tid >> 6);
    const int rblk = W & 63;
    const int rg   = W >> 6;          // 0..127 row-groups of 128 rows
    const int g    = l >> 4;
    const int c    = l & 15;

    // Load the 8 B-fragments of R[rblk] (coalesced 16B per lane).
    bf16x8 bfrag[2][4];
    const bf16x8* rp = reinterpret_cast<const bf16x8*>(Rpk) + (size_t)rblk * 8 * 64 + l;
#pragma unroll
    for (int kf = 0; kf < 2; ++kf)
#pragma unroll
        for (int n = 0; n < 4; ++n)
            bfrag[kf][n] = rp[(kf * 4 + n) * 64];

    const long rowbase = (long)rg * (TILES * 16);
    // Lane's A-frag source: row = l&15 within tile, k-bytes at g*8 (+kf*32).
    const float* xlane = x + (rowbase + (l & 15)) * (long)DD + rblk * 64 + g * 8;

    const f32x4 zero = {0.f, 0.f, 0.f, 0.f};

    f32x4 v[4], vn[4];
#pragma unroll
    for (int q = 0; q < 4; ++q)
        v[q] = *reinterpret_cast<const f32x4*>(xlane + (q >> 1) * 32 + (q & 1) * 4);

#pragma unroll
    for (int t = 0; t < TILES; ++t) {
        // Prefetch next tile's X (independent of compute below).
        if (t + 1 < TILES) {
            const float* xp = xlane + (long)(t + 1) * 16 * DD;
#pragma unroll
            for (int q = 0; q < 4; ++q)
                vn[q] = *reinterpret_cast<const f32x4*>(xp + (q >> 1) * 32 + (q & 1) * 4);
        }

        // Convert to bf16 A-fragments (elements j=0..7 <-> k = 32kf+8g+j).
        bf16x8 a0, a1;
#pragma unroll
        for (int e = 0; e < 4; ++e) {
            a0[e]     = (__bf16)v[0][e];
            a0[e + 4] = (__bf16)v[1][e];
            a1[e]     = (__bf16)v[2][e];
            a1[e + 4] = (__bf16)v[3][e];
        }

        f32x4 acc[4];
#pragma unroll
        for (int n = 0; n < 4; ++n)
            acc[n] = __builtin_amdgcn_mfma_f32_16x16x32_bf16(a0, bfrag[0][n], zero, 0, 0, 0);
#pragma unroll
        for (int n = 0; n < 4; ++n)
            acc[n] = __builtin_amdgcn_mfma_f32_16x16x32_bf16(a1, bfrag[1][n], acc[n], 0, 0, 0);

        // Store: lane holds rows 4g+i, col c+16n of this 16x64 tile.
        float* yl = y + (rowbase + t * 16 + 4 * g) * (long)DD + rblk * 64 + c;
#pragma unroll
        for (int n = 0; n < 4; ++n)
#pragma unroll
            for (int i = 0; i < 4; ++i)
                __builtin_nontemporal_store(acc[n][i], yl + (long)i * DD + n * 16);

#pragma unroll
        for (int q = 0; q < 4; ++q) v[q] = vn[q];
    }
}

extern "C" void kernel_launch(void* const* d_in, const int* in_sizes, int n_in,
                              void* d_out, int out_size, void* d_ws, size_t ws_size,
                              hipStream_t stream) {
    (void)in_sizes; (void)n_in; (void)out_size; (void)ws_size;
    const float* x = (const float*)d_in[0];
    const float* w = (const float*)d_in[1];
    float* y = (float*)d_out;
    __bf16* Rpk = (__bf16*)d_ws;   // 64 rblk * 8 frags * 64 lanes * 8 bf16 = 512 KB

    rot_kernel<<<RB, 256, 0, stream>>>(w, Rpk);

    const int waves  = RB * (MROWS / (TILES * 16));  // 64 * 128 = 8192
    const int blocks = waves / 4;                    // 2048 blocks of 256 thr
    apply_kernel<<<blocks, 256, 0, stream>>>(x, Rpk, y);
}